// Round 4
// baseline (254.483 us; speedup 1.0000x reference)
//
#include <hip/hip_runtime.h>
#include <hip/hip_bf16.h>

#define B_   16
#define K_   50
#define CIN  256
#define F_   76
#define A_   3
#define NCH  85
#define OC   255
#define HW   (F_*F_)
#define NSPLIT 3
#define NBLK (B_*F_*NSPLIT)
#define RAWS 36          // raw stride (32 cols + 4 pad)

// ws floats: Wfrag bf16[65536]=f[0..32768) ; bias[32768..33024) ; labrec[33024..45824) ; partials[45824..)
#define WS_BIAS_F 32768
#define WS_LAB_F  33024
#define WS_PART_F 45824

typedef __attribute__((ext_vector_type(8))) short short8;
typedef __attribute__((ext_vector_type(4))) float f32x4;

__device__ __constant__ float AW9[9] = {1.25f, 2.0f, 4.125f, 3.75f, 7.75f, 7.375f, 14.5f, 19.5f, 46.625f};
__device__ __constant__ float AH9[9] = {1.625f, 3.75f, 2.875f, 7.625f, 5.625f, 14.875f, 11.25f, 24.75f, 40.75f};

__device__ __forceinline__ unsigned short f2bf(float f) {
    union { float f; unsigned int u; } v; v.f = f;
    unsigned int r = v.u + 0x7fffu + ((v.u >> 16) & 1u);
    return (unsigned short)(r >> 16);
}
__device__ __forceinline__ float bf2f(unsigned short b) {
    union { unsigned int u; float f; } v; v.u = ((unsigned int)b) << 16;
    return v.f;
}
__device__ __forceinline__ float sigm(float r) { return 1.0f / (1.0f + __expf(-r)); }
__device__ __forceinline__ float bce_t(float p, float tv) {
    float pc = fminf(fmaxf(p, 1e-12f), 1.0f - 1e-7f);
    return -(tv * __logf(pc) + (1.0f - tv) * __logf(1.0f - pc));
}

// ---------------- prep: W -> bf16 A-fragment order, bias, label records ----------------
__global__ void prep_kernel(const float* __restrict__ conv_w, const float* __restrict__ conv_b,
                            const float* __restrict__ labels, float* __restrict__ ws) {
    int bid = blockIdx.x, t = threadIdx.x;
    if (bid < 256) {
        int idx = bid * 256 + t;
        int mt = idx >> 12, ks = (idx >> 9) & 7, lane = (idx >> 3) & 63, jj = idx & 7;
        int row = mt * 16 + (lane & 15);
        int k   = ks * 32 + (lane >> 4) * 8 + jj;
        float v = (row < OC) ? conv_w[row * CIN + k] : 0.0f;
        ((unsigned short*)ws)[idx] = f2bf(v);
    } else if (bid == 256) {
        ws[WS_BIAS_F + t] = (t < OC) ? conv_b[t] : 0.0f;
    } else { // label records
        for (int idx = t; idx < B_ * K_; idx += 256) {
            const float* L = labels + idx * 5;
            float cls = L[0], xc = L[1], yc = L[2], wl = L[3], hl = L[4];
            float ssum = cls + xc + yc + wl + hl;
            float validf = (ssum > 0.0f) ? 1.0f : 0.0f;
            float tx = xc * F_, ty = yc * F_, tw = wl * F_, th = hl * F_;
            int ii = (int)tx, jj = (int)ty;
            float tarea = tw * th;
            float best = -1.0f; int bn = 0;
            #pragma unroll
            for (int n = 0; n < 9; n++) {
                float inter = fminf(tw, AW9[n]) * fminf(th, AH9[n]);
                float iou = inter / (tarea + AW9[n] * AH9[n] - inter);
                if (iou > best) { best = iou; bn = n; }
            }
            int a = bn % 3;
            float self = (validf != 0.0f && bn < 3) ? 1.0f : 0.0f;
            float* R = ws + WS_LAB_F + idx * 16;
            R[0] = validf; R[1] = tx; R[2] = ty; R[3] = tw; R[4] = th;
            R[5] = self; R[6] = (float)a; R[7] = (float)ii; R[8] = (float)jj;
            R[9] = tx - (float)ii; R[10] = ty - (float)jj;
            R[11] = __logf(tw / AW9[a] + 1e-16f);
            R[12] = __logf(th / AH9[a] + 1e-16f);
            R[13] = sqrtf(2.0f - tarea / (float)HW);
            R[14] = cls; R[15] = 0.0f;
        }
    }
}

// ---------------- fused main: one block per (b, j, col-third) ----------------
__global__ __launch_bounds__(256, 5) void yolo_main(const float* __restrict__ xin,
                                                    const float* __restrict__ ws,
                                                    float* __restrict__ d_out,
                                                    float* __restrict__ part) {
    // UNI: phase1 Xt bf16 [il(32)][k(256)] octet-XOR swizzled (8192 ush)
    //      phase2 raw bf16 [o(255)][stride 36] (9180 ush)
    __shared__ __align__(16) unsigned short UNI[9184];   // 18368 B
    __shared__ float labS[K_ * 16];
    __shared__ float biasS[256];
    __shared__ float redS[4][5];

    const int t = threadIdx.x;
    const int b   = blockIdx.x / (F_ * NSPLIT);
    const int rem = blockIdx.x % (F_ * NSPLIT);
    const int j     = rem / NSPLIT;
    const int third = rem % NSPLIT;
    const int i0   = third * 32;
    const int ncol = (third == 2) ? 12 : 32;
    const int ntl  = (third == 2) ? 1 : 2;

    const float* labrec = ws + WS_LAB_F + b * K_ * 16;
    biasS[t] = ws[WS_BIAS_F + t];
    for (int idx = t; idx < K_ * 16; idx += 256) labS[idx] = labrec[idx];

    // ---------- staging: xin row j cols [i0,i0+ncol) -> Xt bf16, zero-pad il>=ncol ----------
    for (int idx = t; idx < 32 * 32; idx += 256) {
        int co = idx >> 5, il = idx & 31;
        short8 v;
        if (il < ncol) {
            const float* xp = xin + ((size_t)b * CIN + co * 8) * HW + j * F_ + i0 + il;
            #pragma unroll
            for (int jj = 0; jj < 8; jj++) v[jj] = (short)f2bf(xp[jj * HW]);
        } else {
            v = (short8){0,0,0,0,0,0,0,0};
        }
        int phys = co ^ (il & 7);
        *(short8*)&UNI[il * 256 + phys * 8] = v;
    }

    // cooperative zero of this block's out_m region (3 anchors x ncol x 85), contiguous per anchor
    for (int a = 0; a < A_; a++) {
        float2* z = reinterpret_cast<float2*>(d_out + 6 + ((((size_t)(b * A_ + a) * F_ + j) * F_ + i0)) * NCH);
        int nf2 = (ncol * NCH) >> 1;
        for (int idx = t; idx < nf2; idx += 256) z[idx] = make_float2(0.0f, 0.0f);
    }
    __syncthreads();

    // ---------- MFMA K-loop: wave w owns M-tiles w*4..w*4+3, ntl N-tiles ----------
    const int w = t >> 6, lane = t & 63, lr = lane & 15, q = lane >> 4;
    f32x4 acc[4][2];
    #pragma unroll
    for (int m = 0; m < 4; m++)
        #pragma unroll
        for (int n = 0; n < 2; n++) acc[m][n] = (f32x4){0.0f, 0.0f, 0.0f, 0.0f};

    const short8* wf = (const short8*)ws;
    #pragma unroll 2
    for (int ks = 0; ks < 8; ks++) {
        short8 afr[4], bfr[2];
        #pragma unroll
        for (int m = 0; m < 4; m++)
            afr[m] = wf[((w * 4 + m) * 8 + ks) * 64 + lane];
        #pragma unroll
        for (int n = 0; n < 2; n++) {
            if (n < ntl) {
                int nn = n * 16 + lr;
                int phys = (ks * 4 + q) ^ (nn & 7);
                bfr[n] = *(const short8*)&UNI[nn * 256 + phys * 8];
            }
        }
        #pragma unroll
        for (int m = 0; m < 4; m++)
            #pragma unroll
            for (int n = 0; n < 2; n++)
                if (n < ntl)
                    acc[m][n] = __builtin_amdgcn_mfma_f32_16x16x32_bf16(afr[m], bfr[n], acc[m][n], 0, 0, 0);
    }
    __syncthreads();

    // ---------- epilogue: acc (+bias) -> raw bf16 [o][il], stride RAWS ----------
    #pragma unroll
    for (int m = 0; m < 4; m++) {
        #pragma unroll
        for (int n = 0; n < 2; n++) {
            if (n < ntl) {
                int il = n * 16 + lr;
                if (il < ncol) {
                    #pragma unroll
                    for (int r = 0; r < 4; r++) {
                        int o = (w * 4 + m) * 16 + q * 4 + r;
                        if (o < OC) UNI[o * RAWS + il] = f2bf(acc[m][n][r] + biasS[o]);
                    }
                }
            }
        }
    }
    __syncthreads();

    // ---------- phase 2: per-cell losses + out_m ----------
    float lxy = 0.0f, lwh = 0.0f, lobj = 0.0f, lcls = 0.0f, l2 = 0.0f;
    if (t < A_ * ncol) {
        int a = t / ncol, il = t - a * ncol;
        int i = i0 + il;
        const unsigned short* rc = UNI + (a * NCH) * RAWS + il;
        float x   = sigm(bf2f(rc[0 * RAWS]));
        float y   = sigm(bf2f(rc[1 * RAWS]));
        float wr  = bf2f(rc[2 * RAWS]);
        float hr  = bf2f(rc[3 * RAWS]);
        float obj = sigm(bf2f(rc[4 * RAWS]));

        float px = x + (float)i, py = y + (float)j;
        float pw = __expf(wr) * AW9[a], ph = __expf(hr) * AH9[a];
        float areap = pw * ph;

        float maxiou = 0.0f; int mk = -1;
        for (int k = 0; k < K_; k++) {
            const float* R = labS + k * 16;
            float tx = R[1], ty = R[2], tw = R[3], th = R[4];
            if (R[0] != 0.0f) {
                float tlx = fmaxf(px - pw * 0.5f, tx - tw * 0.5f);
                float tly = fmaxf(py - ph * 0.5f, ty - th * 0.5f);
                float brx = fminf(px + pw * 0.5f, tx + tw * 0.5f);
                float bry = fminf(py + ph * 0.5f, ty + th * 0.5f);
                float iw = brx - tlx, ih = bry - tly;
                float inter = (iw > 0.0f && ih > 0.0f) ? iw * ih : 0.0f;
                float iou = inter / (areap + tw * th - inter);
                maxiou = fmaxf(maxiou, iou);
            }
            if (R[5] != 0.0f && (int)R[6] == a && (int)R[7] == i && (int)R[8] == j) mk = k;
        }
        float objmask = (maxiou > 0.7f) ? 0.0f : 1.0f;

        float* om = d_out + 6 + ((((size_t)(b * A_ + a) * F_ + j) * F_ + i)) * NCH;
        if (mk >= 0) {
            const float* R = labS + mk * 16;
            float sc = R[13], sc2 = sc * sc;
            float txv = R[9], tyv = R[10], twv = R[11], thv = R[12];
            int cl = (int)R[14];
            lxy = (bce_t(x, txv) + bce_t(y, tyv)) * sc2;
            float dw = wr - twv, dh = hr - thv;
            lwh = 0.5f * sc2 * (dw * dw + dh * dh);
            float pco = fminf(fmaxf(obj, 1e-12f), 1.0f - 1e-7f);
            lobj = -__logf(pco);
            float dx = x - txv, dy = y - tyv, dob = obj - 1.0f;
            l2 = dx * dx + dy * dy + sc2 * (dw * dw + dh * dh) + dob * dob;
            om[0] = x; om[1] = y; om[2] = wr * sc; om[3] = hr * sc; om[4] = obj;
            for (int c = 0; c < 80; c++) {
                float p = sigm(bf2f(rc[(5 + c) * RAWS]));
                float tcv = (c == cl) ? 1.0f : 0.0f;
                lcls += bce_t(p, tcv);
                float d = p - tcv;
                l2 += d * d;
                om[5 + c] = p;
            }
        } else {
            float oo = obj * objmask;
            if (objmask != 0.0f) {
                float pco = fminf(obj, 1.0f - 1e-7f);
                lobj = -__logf(1.0f - pco);
            }
            l2 = oo * oo;
            om[4] = oo;
        }
    }

    // wave reduce -> LDS -> one partial record per block
    #pragma unroll
    for (int off = 32; off > 0; off >>= 1) {
        lxy  += __shfl_down(lxy, off);
        lwh  += __shfl_down(lwh, off);
        lobj += __shfl_down(lobj, off);
        lcls += __shfl_down(lcls, off);
        l2   += __shfl_down(l2, off);
    }
    if (lane == 0) {
        redS[w][0] = lxy; redS[w][1] = lwh; redS[w][2] = lobj;
        redS[w][3] = lcls; redS[w][4] = l2;
    }
    __syncthreads();
    if (t == 0) {
        float* P = part + (size_t)blockIdx.x * 8;
        #pragma unroll
        for (int q2 = 0; q2 < 5; q2++)
            P[q2] = redS[0][q2] + redS[1][q2] + redS[2][q2] + redS[3][q2];
    }
}

// ---------------- finish: reduce partials -> d_out[0..5] ----------------
__global__ void finish_kernel(const float* __restrict__ part, float* __restrict__ d_out) {
    int t = threadIdx.x;
    float s0 = 0, s1 = 0, s2 = 0, s3 = 0, s4 = 0;
    for (int bidx = t; bidx < NBLK; bidx += 256) {
        const float* P = part + (size_t)bidx * 8;
        s0 += P[0]; s1 += P[1]; s2 += P[2]; s3 += P[3]; s4 += P[4];
    }
    #pragma unroll
    for (int off = 32; off > 0; off >>= 1) {
        s0 += __shfl_down(s0, off); s1 += __shfl_down(s1, off);
        s2 += __shfl_down(s2, off); s3 += __shfl_down(s3, off);
        s4 += __shfl_down(s4, off);
    }
    __shared__ float red[4][5];
    if ((t & 63) == 0) {
        int w = t >> 6;
        red[w][0] = s0; red[w][1] = s1; red[w][2] = s2; red[w][3] = s3; red[w][4] = s4;
    }
    __syncthreads();
    if (t == 0) {
        float r0 = red[0][0] + red[1][0] + red[2][0] + red[3][0];
        float r1 = red[0][1] + red[1][1] + red[2][1] + red[3][1];
        float r2 = red[0][2] + red[1][2] + red[2][2] + red[3][2];
        float r3 = red[0][3] + red[1][3] + red[2][3] + red[3][3];
        float r4 = red[0][4] + red[1][4] + red[2][4] + red[3][4];
        d_out[0] = r0 + r1 + r2 + r3;
        d_out[1] = r0; d_out[2] = r1; d_out[3] = r2; d_out[4] = r3; d_out[5] = r4;
    }
}

extern "C" void kernel_launch(void* const* d_in, const int* in_sizes, int n_in,
                              void* d_out, int out_size, void* d_ws, size_t ws_size,
                              hipStream_t stream) {
    const float* xin    = (const float*)d_in[0];
    const float* labels = (const float*)d_in[1];
    const float* conv_w = (const float*)d_in[2];
    const float* conv_b = (const float*)d_in[3];
    float* out  = (float*)d_out;
    float* ws   = (float*)d_ws;
    float* part = ws + WS_PART_F;

    prep_kernel<<<258, 256, 0, stream>>>(conv_w, conv_b, labels, ws);
    yolo_main<<<NBLK, 256, 0, stream>>>(xin, ws, out, part);
    finish_kernel<<<1, 256, 0, stream>>>(part, out);
}

// Round 5
// 235.901 us; speedup vs baseline: 1.0788x; 1.0788x over previous
//
#include <hip/hip_runtime.h>
#include <hip/hip_bf16.h>

#define B_   16
#define K_   50
#define CIN  256
#define F_   76
#define A_   3
#define NCH  85
#define OC   255
#define HW   (F_*F_)
#define NBLK (B_*F_)
#define RAWS 84

// ws floats: Wfrag bf16[65536]=f[0..32768) ; bias[32768..33024) ; labrec[33024..45824) ; partials[45824..)
#define WS_BIAS_F 32768
#define WS_LAB_F  33024
#define WS_PART_F 45824

typedef __attribute__((ext_vector_type(8))) short short8;
typedef __attribute__((ext_vector_type(4))) float f32x4;

__device__ __constant__ float AW9[9] = {1.25f, 2.0f, 4.125f, 3.75f, 7.75f, 7.375f, 14.5f, 19.5f, 46.625f};
__device__ __constant__ float AH9[9] = {1.625f, 3.75f, 2.875f, 7.625f, 5.625f, 14.875f, 11.25f, 24.75f, 40.75f};

__device__ __forceinline__ unsigned short f2bf(float f) {
    union { float f; unsigned int u; } v; v.f = f;
    unsigned int r = v.u + 0x7fffu + ((v.u >> 16) & 1u);
    return (unsigned short)(r >> 16);
}
__device__ __forceinline__ float bf2f(unsigned short b) {
    union { unsigned int u; float f; } v; v.u = ((unsigned int)b) << 16;
    return v.f;
}
__device__ __forceinline__ float sigm(float r) { return 1.0f / (1.0f + __expf(-r)); }
__device__ __forceinline__ float bce_t(float p, float tv) {
    float pc = fminf(fmaxf(p, 1e-12f), 1.0f - 1e-7f);
    return -(tv * __logf(pc) + (1.0f - tv) * __logf(1.0f - pc));
}

// ---------------- prep: W -> bf16 A-fragment order, bias, label records ----------------
// label record (16 floats): A0={tx,ty,tw,th} A1={valid,fa,fi,fj} B0={txv,tyv,logw,logh} B1={sc,cls,0,0}
__global__ void prep_kernel(const float* __restrict__ conv_w, const float* __restrict__ conv_b,
                            const float* __restrict__ labels, float* __restrict__ ws) {
    int bid = blockIdx.x, t = threadIdx.x;
    if (bid < 256) {
        int idx = bid * 256 + t;
        int mt = idx >> 12, ks = (idx >> 9) & 7, lane = (idx >> 3) & 63, jj = idx & 7;
        int row = mt * 16 + (lane & 15);
        int k   = ks * 32 + (lane >> 4) * 8 + jj;
        float v = (row < OC) ? conv_w[row * CIN + k] : 0.0f;
        ((unsigned short*)ws)[idx] = f2bf(v);
    } else if (bid == 256) {
        ws[WS_BIAS_F + t] = (t < OC) ? conv_b[t] : 0.0f;
    } else { // label records
        for (int idx = t; idx < B_ * K_; idx += 256) {
            const float* L = labels + idx * 5;
            float cls = L[0], xc = L[1], yc = L[2], wl = L[3], hl = L[4];
            float ssum = cls + xc + yc + wl + hl;
            float validf = (ssum > 0.0f) ? 1.0f : 0.0f;
            float tx = xc * F_, ty = yc * F_, tw = wl * F_, th = hl * F_;
            int ii = (int)tx, jj = (int)ty;
            float tarea = tw * th;
            float best = -1.0f; int bn = 0;
            #pragma unroll
            for (int n = 0; n < 9; n++) {
                float inter = fminf(tw, AW9[n]) * fminf(th, AH9[n]);
                float iou = inter / (tarea + AW9[n] * AH9[n] - inter);
                if (iou > best) { best = iou; bn = n; }
            }
            int a = bn % 3;
            bool self = (validf != 0.0f) && (bn < 3);
            float* R = ws + WS_LAB_F + idx * 16;
            R[0] = tx; R[1] = ty; R[2] = tw; R[3] = th;
            R[4] = validf; R[5] = self ? (float)a : -1.0f; R[6] = (float)ii; R[7] = (float)jj;
            R[8] = tx - (float)ii; R[9] = ty - (float)jj;
            R[10] = __logf(tw / AW9[a] + 1e-16f);
            R[11] = __logf(th / AH9[a] + 1e-16f);
            R[12] = sqrtf(2.0f - tarea / (float)HW);
            R[13] = cls; R[14] = 0.0f; R[15] = 0.0f;
        }
    }
}

// ---------------- fused main: one block per (b, j) row ----------------
__global__ __launch_bounds__(256, 3) void yolo_main(const float* __restrict__ xin,
                                                    const float* __restrict__ ws,
                                                    float* __restrict__ d_out,
                                                    float* __restrict__ part) {
    // UNI: phase1 Xt bf16 [il(80)][k(256)] octet-XOR swizzled ; phase2+ raw bf16 [o(255)][stride 84]
    __shared__ __align__(16) unsigned short UNI[OC * RAWS];  // 42840 B
    __shared__ float4 LAB[K_ * 4];                           // 3200 B
    __shared__ float biasS[256];
    __shared__ int   flagS[240];
    __shared__ float omvS[240];
    __shared__ float redS[4][5];

    const int t = threadIdx.x;
    const int b = blockIdx.x / F_;
    const int j = blockIdx.x % F_;

    biasS[t] = ws[WS_BIAS_F + t];
    {
        const float4* wsrec = (const float4*)(ws + WS_LAB_F + b * (K_ * 16));
        if (t < K_ * 4) LAB[t] = wsrec[t];
    }

    // ---------- staging: xin row j -> Xt[i][c] bf16, octet-XOR-swizzled ----------
    for (int idx = t; idx < 32 * F_; idx += 256) {
        int co = idx / F_, i = idx - co * F_;
        const float* xp = xin + ((size_t)b * CIN + co * 8) * HW + j * F_ + i;
        short8 v;
        #pragma unroll
        for (int jj = 0; jj < 8; jj++) v[jj] = (short)f2bf(xp[jj * HW]);
        int phys = co ^ (i & 7);
        *(short8*)&UNI[i * 256 + phys * 8] = v;
    }
    __syncthreads();

    // ---------- MFMA K-loop: wave w owns M-tiles w*4..w*4+3, 5 N-tiles ----------
    const int w = t >> 6, lane = t & 63, lr = lane & 15, q = lane >> 4;
    f32x4 acc[4][5];
    #pragma unroll
    for (int m = 0; m < 4; m++)
        #pragma unroll
        for (int n = 0; n < 5; n++) acc[m][n] = (f32x4){0.0f, 0.0f, 0.0f, 0.0f};

    const short8* wf = (const short8*)ws;
    #pragma unroll 2
    for (int ks = 0; ks < 8; ks++) {
        short8 afr[4], bfr[5];
        #pragma unroll
        for (int m = 0; m < 4; m++)
            afr[m] = wf[((w * 4 + m) * 8 + ks) * 64 + lane];
        #pragma unroll
        for (int n = 0; n < 5; n++) {
            int nn = n * 16 + lr;
            int phys = (ks * 4 + q) ^ (nn & 7);
            bfr[n] = *(const short8*)&UNI[nn * 256 + phys * 8];
        }
        #pragma unroll
        for (int m = 0; m < 4; m++)
            #pragma unroll
            for (int n = 0; n < 5; n++)
                acc[m][n] = __builtin_amdgcn_mfma_f32_16x16x32_bf16(afr[m], bfr[n], acc[m][n], 0, 0, 0);
    }
    __syncthreads();

    // ---------- epilogue: acc (+bias) -> raw bf16 [o][i], stride 84 ----------
    #pragma unroll
    for (int m = 0; m < 4; m++) {
        #pragma unroll
        for (int n = 0; n < 5; n++) {
            int i = n * 16 + lr;
            if (i < F_) {
                #pragma unroll
                for (int r = 0; r < 4; r++) {
                    int o = (w * 4 + m) * 16 + q * 4 + r;
                    if (o < OC) UNI[o * RAWS + i] = f2bf(acc[m][n][r] + biasS[o]);
                }
            }
        }
    }
    __syncthreads();

    // ---------- phase 2: per-cell losses + flags (no out_m writes here) ----------
    float lxy = 0.0f, lwh = 0.0f, lobj = 0.0f, lcls = 0.0f, l2 = 0.0f;
    if (t < A_ * F_) {
        int a = t / F_, i = t - a * F_;
        const unsigned short* rc = UNI + (a * NCH) * RAWS + i;
        float x   = sigm(bf2f(rc[0 * RAWS]));
        float y   = sigm(bf2f(rc[1 * RAWS]));
        float wr  = bf2f(rc[2 * RAWS]);
        float hr  = bf2f(rc[3 * RAWS]);
        float obj = sigm(bf2f(rc[4 * RAWS]));

        float px = x + (float)i, py = y + (float)j;
        float pw = __expf(wr) * AW9[a], ph = __expf(hr) * AH9[a];
        float hpw = pw * 0.5f, hph = ph * 0.5f;
        float areap = pw * ph;
        float fa_t = (float)a, fi_t = (float)i, fj_t = (float)j;

        float maxiou = 0.0f; int mk = -1;
        #pragma unroll 2
        for (int k = 0; k < K_; k++) {
            float4 A0 = LAB[4 * k + 0];
            float4 A1 = LAB[4 * k + 1];
            float tx = A0.x, ty = A0.y, tw = A0.z, th = A0.w;
            float tlx = fmaxf(px - hpw, tx - tw * 0.5f);
            float tly = fmaxf(py - hph, ty - th * 0.5f);
            float brx = fminf(px + hpw, tx + tw * 0.5f);
            float bry = fminf(py + hph, ty + th * 0.5f);
            float iw = brx - tlx, ih = bry - tly;
            float inter = (iw > 0.0f && ih > 0.0f) ? iw * ih : 0.0f;
            float iou = __fdividef(inter, areap + tw * th - inter);
            iou = (A1.x != 0.0f) ? iou : 0.0f;
            maxiou = fmaxf(maxiou, iou);
            bool match = (A1.y == fa_t) & (A1.z == fi_t) & (A1.w == fj_t);
            mk = match ? k : mk;
        }
        float objmask = (maxiou > 0.7f) ? 0.0f : 1.0f;

        if (mk >= 0) {
            float4 B0 = LAB[4 * mk + 2];
            float4 B1 = LAB[4 * mk + 3];
            float sc = B0.x; // careful: sc is B1.x per record layout
            sc = B1.x;
            float sc2 = sc * sc;
            float txv = B0.x, tyv = B0.y, twv = B0.z, thv = B0.w;
            int cl = (int)B1.y;
            lxy = (bce_t(x, txv) + bce_t(y, tyv)) * sc2;
            float dw = wr - twv, dh = hr - thv;
            lwh = 0.5f * sc2 * (dw * dw + dh * dh);
            float pco = fminf(fmaxf(obj, 1e-12f), 1.0f - 1e-7f);
            lobj = -__logf(pco);
            float dx = x - txv, dy = y - tyv, dob = obj - 1.0f;
            l2 = dx * dx + dy * dy + sc2 * (dw * dw + dh * dh) + dob * dob;
            for (int c = 0; c < 80; c++) {
                float p = sigm(bf2f(rc[(5 + c) * RAWS]));
                float tcv = (c == cl) ? 1.0f : 0.0f;
                lcls += bce_t(p, tcv);
                float d = p - tcv;
                l2 += d * d;
            }
            flagS[t] = mk + 1;
            omvS[t]  = obj;
        } else {
            float oo = obj * objmask;
            if (objmask != 0.0f) {
                float pco = fminf(obj, 1.0f - 1e-7f);
                lobj = -__logf(1.0f - pco);
            }
            l2 = oo * oo;
            flagS[t] = 0;
            omvS[t]  = oo;
        }
    }
    __syncthreads();

    // ---------- phase 3: dense coalesced out_m write ----------
    // out_m[(b,a,j,:,:)] is contiguous per anchor: F_*NCH dwords
    for (int a = 0; a < A_; a++) {
        float* dst = d_out + 6 + ((((size_t)(b * A_ + a)) * F_ + j) * F_) * NCH;
        for (int idx = t; idx < F_ * NCH; idx += 256) {
            int i  = idx / NCH;
            int ch = idx - i * NCH;
            int cell = a * F_ + i;
            int flag = flagS[cell];
            float v;
            if (flag == 0) {
                v = (ch == 4) ? omvS[cell] : 0.0f;
            } else {
                float raw = bf2f(UNI[(a * NCH + ch) * RAWS + i]);
                if (ch == 2 || ch == 3) v = raw * LAB[4 * (flag - 1) + 3].x;
                else                    v = sigm(raw);
            }
            dst[idx] = v;
        }
    }

    // wave reduce -> LDS -> one partial record per block
    #pragma unroll
    for (int off = 32; off > 0; off >>= 1) {
        lxy  += __shfl_down(lxy, off);
        lwh  += __shfl_down(lwh, off);
        lobj += __shfl_down(lobj, off);
        lcls += __shfl_down(lcls, off);
        l2   += __shfl_down(l2, off);
    }
    if (lane == 0) {
        redS[w][0] = lxy; redS[w][1] = lwh; redS[w][2] = lobj;
        redS[w][3] = lcls; redS[w][4] = l2;
    }
    __syncthreads();
    if (t == 0) {
        float* P = part + (size_t)blockIdx.x * 8;
        #pragma unroll
        for (int q2 = 0; q2 < 5; q2++)
            P[q2] = redS[0][q2] + redS[1][q2] + redS[2][q2] + redS[3][q2];
    }
}

// ---------------- finish: reduce partials -> d_out[0..5] ----------------
__global__ void finish_kernel(const float* __restrict__ part, float* __restrict__ d_out) {
    int t = threadIdx.x;
    float s0 = 0, s1 = 0, s2 = 0, s3 = 0, s4 = 0;
    for (int bidx = t; bidx < NBLK; bidx += 256) {
        const float* P = part + (size_t)bidx * 8;
        s0 += P[0]; s1 += P[1]; s2 += P[2]; s3 += P[3]; s4 += P[4];
    }
    #pragma unroll
    for (int off = 32; off > 0; off >>= 1) {
        s0 += __shfl_down(s0, off); s1 += __shfl_down(s1, off);
        s2 += __shfl_down(s2, off); s3 += __shfl_down(s3, off);
        s4 += __shfl_down(s4, off);
    }
    __shared__ float red[4][5];
    if ((t & 63) == 0) {
        int w = t >> 6;
        red[w][0] = s0; red[w][1] = s1; red[w][2] = s2; red[w][3] = s3; red[w][4] = s4;
    }
    __syncthreads();
    if (t == 0) {
        float r0 = red[0][0] + red[1][0] + red[2][0] + red[3][0];
        float r1 = red[0][1] + red[1][1] + red[2][1] + red[3][1];
        float r2 = red[0][2] + red[1][2] + red[2][2] + red[3][2];
        float r3 = red[0][3] + red[1][3] + red[2][3] + red[3][3];
        float r4 = red[0][4] + red[1][4] + red[2][4] + red[3][4];
        d_out[0] = r0 + r1 + r2 + r3;
        d_out[1] = r0; d_out[2] = r1; d_out[3] = r2; d_out[4] = r3; d_out[5] = r4;
    }
}

extern "C" void kernel_launch(void* const* d_in, const int* in_sizes, int n_in,
                              void* d_out, int out_size, void* d_ws, size_t ws_size,
                              hipStream_t stream) {
    const float* xin    = (const float*)d_in[0];
    const float* labels = (const float*)d_in[1];
    const float* conv_w = (const float*)d_in[2];
    const float* conv_b = (const float*)d_in[3];
    float* out  = (float*)d_out;
    float* ws   = (float*)d_ws;
    float* part = ws + WS_PART_F;

    prep_kernel<<<258, 256, 0, stream>>>(conv_w, conv_b, labels, ws);
    yolo_main<<<NBLK, 256, 0, stream>>>(xin, ws, out, part);
    finish_kernel<<<1, 256, 0, stream>>>(part, out);
}

// Round 6
// 234.749 us; speedup vs baseline: 1.0841x; 1.0049x over previous
//
#include <hip/hip_runtime.h>
#include <hip/hip_bf16.h>

#define B_   16
#define K_   50
#define CIN  256
#define F_   76
#define A_   3
#define NCH  85
#define OC   255
#define HW   (F_*F_)
#define NBLK (B_*F_)
#define NCELL (A_*F_)            // 228

// ws floats: Wfrag bf16[65536]=f[0..32768) ; bias[32768..33024) ; labrec[33024..45824) ; partials[45824..)
#define WS_BIAS_F 32768
#define WS_LAB_F  33024
#define WS_PART_F 45824

typedef __attribute__((ext_vector_type(8))) short short8;
typedef __attribute__((ext_vector_type(4))) float f32x4;

__device__ __constant__ float AW9[9] = {1.25f, 2.0f, 4.125f, 3.75f, 7.75f, 7.375f, 14.5f, 19.5f, 46.625f};
__device__ __constant__ float AH9[9] = {1.625f, 3.75f, 2.875f, 7.625f, 5.625f, 14.875f, 11.25f, 24.75f, 40.75f};

__device__ __forceinline__ unsigned short f2bf(float f) {
    union { float f; unsigned int u; } v; v.f = f;
    unsigned int r = v.u + 0x7fffu + ((v.u >> 16) & 1u);
    return (unsigned short)(r >> 16);
}
__device__ __forceinline__ float bf2f(unsigned short b) {
    union { unsigned int u; float f; } v; v.u = ((unsigned int)b) << 16;
    return v.f;
}
__device__ __forceinline__ float sigm(float r) { return 1.0f / (1.0f + __expf(-r)); }
__device__ __forceinline__ float bce_t(float p, float tv) {
    float pc = fminf(fmaxf(p, 1e-12f), 1.0f - 1e-7f);
    return -(tv * __logf(pc) + (1.0f - tv) * __logf(1.0f - pc));
}

// ---------------- prep: W -> bf16 A-fragment order, bias, label records ----------------
// record: A0={tx,ty,tw,th} A1={valid, fa(-1 if not pos), fi, fj} B0={txv,tyv,logw,logh} B1={sc,cls,0,0}
__global__ void prep_kernel(const float* __restrict__ conv_w, const float* __restrict__ conv_b,
                            const float* __restrict__ labels, float* __restrict__ ws) {
    int bid = blockIdx.x, t = threadIdx.x;
    if (bid < 256) {
        int idx = bid * 256 + t;
        int mt = idx >> 12, ks = (idx >> 9) & 7, lane = (idx >> 3) & 63, jj = idx & 7;
        int row = mt * 16 + (lane & 15);
        int k   = ks * 32 + (lane >> 4) * 8 + jj;
        float v = (row < OC) ? conv_w[row * CIN + k] : 0.0f;
        ((unsigned short*)ws)[idx] = f2bf(v);
    } else if (bid == 256) {
        ws[WS_BIAS_F + t] = (t < OC) ? conv_b[t] : 0.0f;
    } else {
        for (int idx = t; idx < B_ * K_; idx += 256) {
            const float* L = labels + idx * 5;
            float cls = L[0], xc = L[1], yc = L[2], wl = L[3], hl = L[4];
            float ssum = cls + xc + yc + wl + hl;
            float validf = (ssum > 0.0f) ? 1.0f : 0.0f;
            float tx = xc * F_, ty = yc * F_, tw = wl * F_, th = hl * F_;
            int ii = (int)tx, jj = (int)ty;
            float tarea = tw * th;
            float best = -1.0f; int bn = 0;
            #pragma unroll
            for (int n = 0; n < 9; n++) {
                float inter = fminf(tw, AW9[n]) * fminf(th, AH9[n]);
                float iou = inter / (tarea + AW9[n] * AH9[n] - inter);
                if (iou > best) { best = iou; bn = n; }
            }
            int a = bn % 3;
            bool self = (validf != 0.0f) && (bn < 3);
            float* R = ws + WS_LAB_F + idx * 16;
            R[0] = tx; R[1] = ty; R[2] = tw; R[3] = th;
            R[4] = validf; R[5] = self ? (float)a : -1.0f; R[6] = (float)ii; R[7] = (float)jj;
            R[8] = tx - (float)ii; R[9] = ty - (float)jj;
            R[10] = __logf(tw / AW9[a] + 1e-16f);
            R[11] = __logf(th / AH9[a] + 1e-16f);
            R[12] = sqrtf(2.0f - tarea / (float)HW);
            R[13] = cls; R[14] = 0.0f; R[15] = 0.0f;
        }
    }
}

// ---------------- fused main: one block (512 thr, 8 waves) per (b, j) row ----------------
__global__ __launch_bounds__(512, 4) void yolo_main(const float* __restrict__ xin,
                                                    const float* __restrict__ ws,
                                                    float* __restrict__ d_out,
                                                    float* __restrict__ part) {
    // UNI: phase1 Xt bf16 [i(76)][k(256)] octet-XOR swizzled (19456 ush)
    //      phase2+ raw bf16 in out_m order [a][i][ch] (19380 ush)
    __shared__ __align__(16) unsigned short UNI[19456];      // 38912 B
    __shared__ float4 LAB[K_ * 4];                           // 3200 B
    __shared__ float biasS[256];
    __shared__ int   flagS[NCELL];
    __shared__ float omvS[NCELL];
    __shared__ float redS[8][5];

    const int t = threadIdx.x;
    const int b = blockIdx.x / F_;
    const int j = blockIdx.x % F_;

    if (t < 256) biasS[t] = ws[WS_BIAS_F + t];
    if (t < K_ * 4) LAB[t] = ((const float4*)(ws + WS_LAB_F + b * (K_ * 16)))[t];

    // ---------- staging: xin row j -> Xt[i][k] bf16, octet-XOR-swizzled ----------
    for (int idx = t; idx < 32 * F_; idx += 512) {
        int co = idx / F_, i = idx - co * F_;
        const float* xp = xin + ((size_t)b * CIN + co * 8) * HW + j * F_ + i;
        short8 v;
        #pragma unroll
        for (int jj = 0; jj < 8; jj++) v[jj] = (short)f2bf(xp[jj * HW]);
        int phys = co ^ (i & 7);
        *(short8*)&UNI[i * 256 + phys * 8] = v;
    }
    __syncthreads();

    // ---------- MFMA K-loop: wave w owns M-tiles {w, w+8}, 5 N-tiles ----------
    const int w = t >> 6, lane = t & 63, lr = lane & 15, q = lane >> 4;
    f32x4 acc[2][5];
    #pragma unroll
    for (int m = 0; m < 2; m++)
        #pragma unroll
        for (int n = 0; n < 5; n++) acc[m][n] = (f32x4){0.0f, 0.0f, 0.0f, 0.0f};

    const short8* wf = (const short8*)ws;
    #pragma unroll 2
    for (int ks = 0; ks < 8; ks++) {
        short8 afr[2], bfr[5];
        #pragma unroll
        for (int m = 0; m < 2; m++)
            afr[m] = wf[((w + m * 8) * 8 + ks) * 64 + lane];
        #pragma unroll
        for (int n = 0; n < 5; n++) {
            int nn = n * 16 + lr;
            int phys = (ks * 4 + q) ^ (nn & 7);
            bfr[n] = *(const short8*)&UNI[nn * 256 + phys * 8];
        }
        #pragma unroll
        for (int m = 0; m < 2; m++)
            #pragma unroll
            for (int n = 0; n < 5; n++)
                acc[m][n] = __builtin_amdgcn_mfma_f32_16x16x32_bf16(afr[m], bfr[n], acc[m][n], 0, 0, 0);
    }
    __syncthreads();   // B-reads done before overwriting UNI with raw

    // ---------- epilogue: acc (+bias) -> raw bf16 in [a][i][ch] (out_m) order ----------
    #pragma unroll
    for (int m = 0; m < 2; m++) {
        #pragma unroll
        for (int n = 0; n < 5; n++) {
            int i = n * 16 + lr;
            if (i < F_) {
                #pragma unroll
                for (int r = 0; r < 4; r++) {
                    int o = (w + m * 8) * 16 + q * 4 + r;
                    if (o < OC) {
                        int a  = o / NCH;
                        int ch = o - a * NCH;
                        UNI[(a * F_ + i) * NCH + ch] = f2bf(acc[m][n][r] + biasS[o]);
                    }
                }
            }
        }
    }
    __syncthreads();

    // ---------- phase 2: per-cell losses + flags ----------
    float lxy = 0.0f, lwh = 0.0f, lobj = 0.0f, lcls = 0.0f, l2 = 0.0f;
    if (t < NCELL) {
        int a = t / F_, i = t - a * F_;
        const unsigned short* rc = UNI + t * NCH;     // contiguous channels
        float x   = sigm(bf2f(rc[0]));
        float y   = sigm(bf2f(rc[1]));
        float wr  = bf2f(rc[2]);
        float hr  = bf2f(rc[3]);
        float obj = sigm(bf2f(rc[4]));

        float px = x + (float)i, py = y + (float)j;
        float pw = __expf(wr) * AW9[a], ph = __expf(hr) * AH9[a];
        float hpw = pw * 0.5f, hph = ph * 0.5f;
        float areap = pw * ph;
        float fa_t = (float)a, fi_t = (float)i, fj_t = (float)j;

        float maxiou = 0.0f; int mk = -1;
        #pragma unroll 2
        for (int k = 0; k < K_; k++) {
            float4 A0 = LAB[4 * k + 0];
            float4 A1 = LAB[4 * k + 1];
            float tx = A0.x, ty = A0.y, tw = A0.z, th = A0.w;
            float tlx = fmaxf(px - hpw, tx - tw * 0.5f);
            float tly = fmaxf(py - hph, ty - th * 0.5f);
            float brx = fminf(px + hpw, tx + tw * 0.5f);
            float bry = fminf(py + hph, ty + th * 0.5f);
            float iw = brx - tlx, ih = bry - tly;
            float inter = (iw > 0.0f && ih > 0.0f) ? iw * ih : 0.0f;
            float iou = __fdividef(inter, areap + tw * th - inter);
            iou = (A1.x != 0.0f) ? iou : 0.0f;
            maxiou = fmaxf(maxiou, iou);
            bool match = (A1.y == fa_t) & (A1.z == fi_t) & (A1.w == fj_t);
            mk = match ? k : mk;
        }
        float objmask = (maxiou > 0.7f) ? 0.0f : 1.0f;

        if (mk >= 0) {
            float4 B0 = LAB[4 * mk + 2];
            float4 B1 = LAB[4 * mk + 3];
            float sc = B1.x, sc2 = sc * sc;
            float txv = B0.x, tyv = B0.y, twv = B0.z, thv = B0.w;
            int cl = (int)B1.y;
            lxy = (bce_t(x, txv) + bce_t(y, tyv)) * sc2;
            float dw = wr - twv, dh = hr - thv;
            lwh = 0.5f * sc2 * (dw * dw + dh * dh);
            float pco = fminf(fmaxf(obj, 1e-12f), 1.0f - 1e-7f);
            lobj = -__logf(pco);
            float dx = x - txv, dy = y - tyv, dob = obj - 1.0f;
            l2 = dx * dx + dy * dy + sc2 * (dw * dw + dh * dh) + dob * dob;
            for (int c = 0; c < 80; c++) {
                float p = sigm(bf2f(rc[5 + c]));
                float tcv = (c == cl) ? 1.0f : 0.0f;
                lcls += bce_t(p, tcv);
                float d = p - tcv;
                l2 += d * d;
            }
            flagS[t] = mk + 1;
            omvS[t]  = obj;
        } else {
            float oo = obj * objmask;
            if (objmask != 0.0f) {
                float pco = fminf(obj, 1.0f - 1e-7f);
                lobj = -__logf(1.0f - pco);
            }
            l2 = oo * oo;
            flagS[t] = 0;
            omvS[t]  = oo;
        }
    }
    __syncthreads();

    // ---------- phase 3: dense coalesced out_m write (float2) ----------
    for (int a = 0; a < A_; a++) {
        float2* dst = (float2*)(d_out + 6 + (size_t)((b * A_ + a) * F_ + j) * F_ * NCH);
        for (int idx2 = t; idx2 < (F_ * NCH) / 2; idx2 += 512) {
            int p = idx2 << 1;
            int i0 = p / NCH;
            int c0 = p - i0 * NCH;
            int i1 = i0, c1 = c0 + 1;
            if (c1 == NCH) { i1++; c1 = 0; }
            float v[2];
            int iv[2] = {i0, i1}, cv[2] = {c0, c1};
            #pragma unroll
            for (int e = 0; e < 2; e++) {
                int cell = a * F_ + iv[e];
                int flag = flagS[cell];
                if (flag == 0) {
                    v[e] = (cv[e] == 4) ? omvS[cell] : 0.0f;
                } else {
                    float raw = bf2f(UNI[cell * NCH + cv[e]]);
                    if (cv[e] == 2 || cv[e] == 3) v[e] = raw * LAB[4 * (flag - 1) + 3].x;
                    else                          v[e] = sigm(raw);
                }
            }
            dst[idx2] = make_float2(v[0], v[1]);
        }
    }

    // wave reduce -> LDS -> one partial record per block
    #pragma unroll
    for (int off = 32; off > 0; off >>= 1) {
        lxy  += __shfl_down(lxy, off);
        lwh  += __shfl_down(lwh, off);
        lobj += __shfl_down(lobj, off);
        lcls += __shfl_down(lcls, off);
        l2   += __shfl_down(l2, off);
    }
    if (lane == 0) {
        redS[w][0] = lxy; redS[w][1] = lwh; redS[w][2] = lobj;
        redS[w][3] = lcls; redS[w][4] = l2;
    }
    __syncthreads();
    if (t == 0) {
        float* P = part + (size_t)blockIdx.x * 8;
        #pragma unroll
        for (int q2 = 0; q2 < 5; q2++) {
            float s = 0.0f;
            #pragma unroll
            for (int ww = 0; ww < 8; ww++) s += redS[ww][q2];
            P[q2] = s;
        }
    }
}

// ---------------- finish: reduce partials -> d_out[0..5] ----------------
__global__ void finish_kernel(const float* __restrict__ part, float* __restrict__ d_out) {
    int t = threadIdx.x;
    float s0 = 0, s1 = 0, s2 = 0, s3 = 0, s4 = 0;
    for (int bidx = t; bidx < NBLK; bidx += 256) {
        const float* P = part + (size_t)bidx * 8;
        s0 += P[0]; s1 += P[1]; s2 += P[2]; s3 += P[3]; s4 += P[4];
    }
    #pragma unroll
    for (int off = 32; off > 0; off >>= 1) {
        s0 += __shfl_down(s0, off); s1 += __shfl_down(s1, off);
        s2 += __shfl_down(s2, off); s3 += __shfl_down(s3, off);
        s4 += __shfl_down(s4, off);
    }
    __shared__ float red[4][5];
    if ((t & 63) == 0) {
        int w = t >> 6;
        red[w][0] = s0; red[w][1] = s1; red[w][2] = s2; red[w][3] = s3; red[w][4] = s4;
    }
    __syncthreads();
    if (t == 0) {
        float r0 = red[0][0] + red[1][0] + red[2][0] + red[3][0];
        float r1 = red[0][1] + red[1][1] + red[2][1] + red[3][1];
        float r2 = red[0][2] + red[1][2] + red[2][2] + red[3][2];
        float r3 = red[0][3] + red[1][3] + red[2][3] + red[3][3];
        float r4 = red[0][4] + red[1][4] + red[2][4] + red[3][4];
        d_out[0] = r0 + r1 + r2 + r3;
        d_out[1] = r0; d_out[2] = r1; d_out[3] = r2; d_out[4] = r3; d_out[5] = r4;
    }
}

extern "C" void kernel_launch(void* const* d_in, const int* in_sizes, int n_in,
                              void* d_out, int out_size, void* d_ws, size_t ws_size,
                              hipStream_t stream) {
    const float* xin    = (const float*)d_in[0];
    const float* labels = (const float*)d_in[1];
    const float* conv_w = (const float*)d_in[2];
    const float* conv_b = (const float*)d_in[3];
    float* out  = (float*)d_out;
    float* ws   = (float*)d_ws;
    float* part = ws + WS_PART_F;

    prep_kernel<<<258, 256, 0, stream>>>(conv_w, conv_b, labels, ws);
    yolo_main<<<NBLK, 512, 0, stream>>>(xin, ws, out, part);
    finish_kernel<<<1, 256, 0, stream>>>(part, out);
}

// Round 7
// 213.725 us; speedup vs baseline: 1.1907x; 1.0984x over previous
//
#include <hip/hip_runtime.h>
#include <hip/hip_bf16.h>

#define B_   16
#define K_   50
#define CIN  256
#define F_   76
#define A_   3
#define NCH  85
#define OC   255
#define HW   (F_*F_)
#define NBLK (B_*F_)
#define NCELL (A_*F_)            // 228
#define SLAB (F_*NCH)            // 6460 floats per (b,a,j)

// ws floats: Wt bf16[256][256]=f[0..32768) ; bias[32768..33024) ; labrec[33024..45824) ;
//            partials[45824..55552) ; W15frag bf16[4096]=f[55552..57600)
#define WS_BIAS_F 32768
#define WS_LAB_F  33024
#define WS_PART_F 45824
#define WS_W15_F  55552

typedef __attribute__((ext_vector_type(8))) short short8;
typedef __attribute__((ext_vector_type(4))) float f32x4;

__device__ __constant__ float AW9[9] = {1.25f, 2.0f, 4.125f, 3.75f, 7.75f, 7.375f, 14.5f, 19.5f, 46.625f};
__device__ __constant__ float AH9[9] = {1.625f, 3.75f, 2.875f, 7.625f, 5.625f, 14.875f, 11.25f, 24.75f, 40.75f};

__device__ __forceinline__ unsigned short f2bf(float f) {
    union { float f; unsigned int u; } v; v.f = f;
    unsigned int r = v.u + 0x7fffu + ((v.u >> 16) & 1u);
    return (unsigned short)(r >> 16);
}
__device__ __forceinline__ float bf2f(unsigned short b) {
    union { unsigned int u; float f; } v; v.u = ((unsigned int)b) << 16;
    return v.f;
}
__device__ __forceinline__ float sigm(float r) { return 1.0f / (1.0f + __expf(-r)); }
__device__ __forceinline__ float bce_t(float p, float tv) {
    float pc = fminf(fmaxf(p, 1e-12f), 1.0f - 1e-7f);
    return -(tv * __logf(pc) + (1.0f - tv) * __logf(1.0f - pc));
}

// ---------------- prep ----------------
// labrec: A0={tx,ty,tw,th} A1={valid, fa(-1 if not pos), fi, fj} B0={txv,tyv,logw,logh} B1={sc,cls,0,0}
// W15 row r (r<15): orig o = (r/5)*85 + r%5  (box+obj channels of the 3 anchors)
__global__ void prep_kernel(const float* __restrict__ conv_w, const float* __restrict__ conv_b,
                            const float* __restrict__ labels, float* __restrict__ ws) {
    int bid = blockIdx.x, t = threadIdx.x;
    if (bid < 256) {
        // Wt bf16 [k][o], k = bid, o = t (o=255 pad)
        float v = (t < OC) ? conv_w[t * CIN + bid] : 0.0f;
        ((unsigned short*)ws)[bid * 256 + t] = f2bf(v);
    } else if (bid == 256) {
        ws[WS_BIAS_F + t] = (t < OC) ? conv_b[t] : 0.0f;
    } else if (bid == 257) {
        for (int idx = t; idx < B_ * K_; idx += 256) {
            const float* L = labels + idx * 5;
            float cls = L[0], xc = L[1], yc = L[2], wl = L[3], hl = L[4];
            float ssum = cls + xc + yc + wl + hl;
            float validf = (ssum > 0.0f) ? 1.0f : 0.0f;
            float tx = xc * F_, ty = yc * F_, tw = wl * F_, th = hl * F_;
            int ii = (int)tx, jj = (int)ty;
            float tarea = tw * th;
            float best = -1.0f; int bn = 0;
            #pragma unroll
            for (int n = 0; n < 9; n++) {
                float inter = fminf(tw, AW9[n]) * fminf(th, AH9[n]);
                float iou = inter / (tarea + AW9[n] * AH9[n] - inter);
                if (iou > best) { best = iou; bn = n; }
            }
            int a = bn % 3;
            bool self = (validf != 0.0f) && (bn < 3);
            float* R = ws + WS_LAB_F + idx * 16;
            R[0] = tx; R[1] = ty; R[2] = tw; R[3] = th;
            R[4] = validf; R[5] = self ? (float)a : -1.0f; R[6] = (float)ii; R[7] = (float)jj;
            R[8] = tx - (float)ii; R[9] = ty - (float)jj;
            R[10] = __logf(tw / AW9[a] + 1e-16f);
            R[11] = __logf(th / AH9[a] + 1e-16f);
            R[12] = sqrtf(2.0f - tarea / (float)HW);
            R[13] = cls; R[14] = 0.0f; R[15] = 0.0f;
        }
    } else { // bid == 258 : W15 A-fragments [ks(8)][lane(64)][jj(8)]
        unsigned short* wf = (unsigned short*)(ws + WS_W15_F);
        for (int idx = t; idx < 4096; idx += 256) {
            int ks = idx >> 9, lane = (idx >> 3) & 63, jj = idx & 7;
            int row = lane & 15;
            int k = ks * 32 + (lane >> 4) * 8 + jj;
            float v = 0.0f;
            if (row < 15) v = conv_w[((row / 5) * NCH + (row % 5)) * CIN + k];
            wf[idx] = f2bf(v);
        }
    }
}

// ---------------- conv5: M=16(15) GEMM over all positions; raw5 -> out_m slab a=0 prefix ----------------
__global__ __launch_bounds__(256) void conv5_kernel(const float* __restrict__ xin,
                                                    const float* __restrict__ ws,
                                                    float* __restrict__ d_out) {
    const int w = threadIdx.x >> 6, lane = threadIdx.x & 63;
    const int lr = lane & 15, q = lane >> 4;
    const int T = blockIdx.x * 4 + w;        // 0..5775
    const int b = T / 361;
    const int col0 = (T - b * 361) * 16;

    const unsigned short* wf15 = (const unsigned short*)(ws + WS_W15_F);
    short8 afr[8];
    #pragma unroll
    for (int ks = 0; ks < 8; ks++)
        afr[ks] = *(const short8*)&wf15[(ks * 64 + lane) * 8];

    f32x4 acc = (f32x4){0.0f, 0.0f, 0.0f, 0.0f};
    const float* xbase = xin + (size_t)b * CIN * HW + col0 + lr;
    #pragma unroll
    for (int ks = 0; ks < 8; ks++) {
        int kb = ks * 32 + q * 8;
        float xv[8];
        #pragma unroll
        for (int jj = 0; jj < 8; jj++) xv[jj] = xbase[(size_t)(kb + jj) * HW];
        union { short8 s; __hip_bfloat162 h[4]; } u;
        #pragma unroll
        for (int p = 0; p < 4; p++)
            u.h[p] = __float22bfloat162_rn(make_float2(xv[2 * p], xv[2 * p + 1]));
        acc = __builtin_amdgcn_mfma_f32_16x16x32_bf16(afr[ks], u.s, acc, 0, 0, 0);
    }

    const int pos = col0 + lr;
    const int j = pos / F_, i = pos - j * F_;
    float* slab0 = d_out + 6 + (size_t)((b * A_) * F_ + j) * SLAB;   // exclusive (b,j) temp region
    const float* biasg = ws + WS_BIAS_F;
    #pragma unroll
    for (int r = 0; r < 4; r++) {
        int row = q * 4 + r;
        if (row < 15) {
            int o = (row / 5) * NCH + (row % 5);
            slab0[row * F_ + i] = acc[r] + biasg[o];
        }
    }
}

// ---------------- finalize: losses + dense out_m + sparse matched cells ----------------
__global__ __launch_bounds__(256) void finalize_kernel(const float* __restrict__ xin,
                                                       const float* __restrict__ ws,
                                                       float* __restrict__ d_out,
                                                       float* __restrict__ part) {
    __shared__ float raw5S[15 * F_];     // 4560 B
    __shared__ float4 LAB[K_ * 4];       // 3200 B
    __shared__ int   flagS[NCELL];
    __shared__ float omvS[NCELL];
    __shared__ float xcolS[256];
    __shared__ float redS[4][5];

    const int t = threadIdx.x;
    const int b = blockIdx.x / F_;
    const int j = blockIdx.x % F_;

    const float* rawg = d_out + 6 + (size_t)((b * A_) * F_ + j) * SLAB;
    for (int idx = t; idx < 15 * F_; idx += 256) raw5S[idx] = rawg[idx];
    if (t < K_ * 4) LAB[t] = ((const float4*)(ws + WS_LAB_F + b * (K_ * 16)))[t];
    __syncthreads();

    // ---------- phase 2: per-cell losses + flags ----------
    float lxy = 0.0f, lwh = 0.0f, lobj = 0.0f, lcls = 0.0f, l2 = 0.0f;
    if (t < NCELL) {
        int a = t / F_, i = t - a * F_;
        float x   = sigm(raw5S[(a * 5 + 0) * F_ + i]);
        float y   = sigm(raw5S[(a * 5 + 1) * F_ + i]);
        float wr  = raw5S[(a * 5 + 2) * F_ + i];
        float hr  = raw5S[(a * 5 + 3) * F_ + i];
        float obj = sigm(raw5S[(a * 5 + 4) * F_ + i]);

        float px = x + (float)i, py = y + (float)j;
        float pw = __expf(wr) * AW9[a], ph = __expf(hr) * AH9[a];
        float hpw = pw * 0.5f, hph = ph * 0.5f;
        float areap = pw * ph;
        float fa_t = (float)a, fi_t = (float)i, fj_t = (float)j;

        float maxiou = 0.0f; int mk = -1;
        #pragma unroll 2
        for (int k = 0; k < K_; k++) {
            float4 A0 = LAB[4 * k + 0];
            float4 A1 = LAB[4 * k + 1];
            float tx = A0.x, ty = A0.y, tw = A0.z, th = A0.w;
            float tlx = fmaxf(px - hpw, tx - tw * 0.5f);
            float tly = fmaxf(py - hph, ty - th * 0.5f);
            float brx = fminf(px + hpw, tx + tw * 0.5f);
            float bry = fminf(py + hph, ty + th * 0.5f);
            float iw = brx - tlx, ih = bry - tly;
            float inter = (iw > 0.0f && ih > 0.0f) ? iw * ih : 0.0f;
            float iou = __fdividef(inter, areap + tw * th - inter);
            iou = (A1.x != 0.0f) ? iou : 0.0f;
            maxiou = fmaxf(maxiou, iou);
            bool match = (A1.y == fa_t) & (A1.z == fi_t) & (A1.w == fj_t);
            mk = match ? k : mk;
        }
        float objmask = (maxiou > 0.7f) ? 0.0f : 1.0f;

        if (mk >= 0) {
            float4 B0 = LAB[4 * mk + 2];
            float4 B1 = LAB[4 * mk + 3];
            float sc = B1.x, sc2 = sc * sc;
            float txv = B0.x, tyv = B0.y, twv = B0.z, thv = B0.w;
            lxy = (bce_t(x, txv) + bce_t(y, tyv)) * sc2;
            float dw = wr - twv, dh = hr - thv;
            lwh = 0.5f * sc2 * (dw * dw + dh * dh);
            float pco = fminf(fmaxf(obj, 1e-12f), 1.0f - 1e-7f);
            lobj = -__logf(pco);
            float dx = x - txv, dy = y - tyv, dob = obj - 1.0f;
            l2 = dx * dx + dy * dy + sc2 * (dw * dw + dh * dh) + dob * dob;
            flagS[t] = mk + 1;
            omvS[t]  = obj;
        } else {
            float oo = obj * objmask;
            if (objmask != 0.0f) {
                float pco = fminf(obj, 1.0f - 1e-7f);
                lobj = -__logf(1.0f - pco);
            }
            l2 = oo * oo;
            flagS[t] = 0;
            omvS[t]  = oo;
        }
    }
    __syncthreads();

    // ---------- phase 3a: dense out_m write (overwrites raw5 temp; raw5S already in LDS) ----------
    for (int a = 0; a < A_; a++) {
        float2* dst = (float2*)(d_out + 6 + (size_t)((b * A_ + a) * F_ + j) * SLAB);
        for (int idx2 = t; idx2 < SLAB / 2; idx2 += 256) {
            int p = idx2 << 1;
            int i0 = p / NCH, c0 = p - i0 * NCH;
            int i1 = i0, c1 = c0 + 1;
            if (c1 == NCH) { i1++; c1 = 0; }
            float v0 = (c0 == 4) ? omvS[a * F_ + i0] : 0.0f;
            float v1 = (c1 == 4) ? omvS[a * F_ + i1] : 0.0f;
            dst[idx2] = make_float2(v0, v1);
        }
    }
    __threadfence_block();
    __syncthreads();

    // ---------- phase 3b: matched labels (rare): class dots + sparse overwrite ----------
    const unsigned short* Wtg = (const unsigned short*)ws;
    const float* biasg = ws + WS_BIAS_F;
    for (int k = 0; k < K_; k++) {
        float4 A1 = LAB[4 * k + 1];                 // block-uniform
        int fa = (int)A1.y;
        if (fa < 0) continue;
        if ((int)A1.w != j) continue;
        int fi = (int)A1.z;
        int cell = fa * F_ + fi;
        if (flagS[cell] != k + 1) continue;         // superseded by a later label

        xcolS[t] = xin[((size_t)b * CIN + t) * HW + j * F_ + fi];
        __syncthreads();
        float4 B1 = LAB[4 * k + 3];
        float sc = B1.x; int cl = (int)B1.y;
        if (t < NCH) {
            float v; int chout;
            if (t < 80) {
                int o = fa * NCH + 5 + t;
                float accv = biasg[o];
                #pragma unroll 8
                for (int kk = 0; kk < 256; kk++)
                    accv += bf2f(Wtg[kk * 256 + o]) * xcolS[kk];
                float p = sigm(accv);
                float tcv = (t == cl) ? 1.0f : 0.0f;
                lcls += bce_t(p, tcv);
                float d = p - tcv;
                l2 += d * d;
                v = p; chout = 5 + t;
            } else {
                int ch = t - 80;
                float raw = raw5S[(fa * 5 + ch) * F_ + fi];
                v = (ch == 2 || ch == 3) ? raw * sc : sigm(raw);
                chout = ch;
            }
            d_out[6 + (size_t)((b * A_ + fa) * F_ + j) * SLAB + fi * NCH + chout] = v;
        }
        __syncthreads();                            // protect xcolS reuse
    }

    // ---------- reduction -> partials ----------
    const int w = t >> 6, lane = t & 63;
    #pragma unroll
    for (int off = 32; off > 0; off >>= 1) {
        lxy  += __shfl_down(lxy, off);
        lwh  += __shfl_down(lwh, off);
        lobj += __shfl_down(lobj, off);
        lcls += __shfl_down(lcls, off);
        l2   += __shfl_down(l2, off);
    }
    if (lane == 0) {
        redS[w][0] = lxy; redS[w][1] = lwh; redS[w][2] = lobj;
        redS[w][3] = lcls; redS[w][4] = l2;
    }
    __syncthreads();
    if (t == 0) {
        float* P = part + (size_t)blockIdx.x * 8;
        #pragma unroll
        for (int q2 = 0; q2 < 5; q2++)
            P[q2] = redS[0][q2] + redS[1][q2] + redS[2][q2] + redS[3][q2];
    }
}

// ---------------- finish ----------------
__global__ void finish_kernel(const float* __restrict__ part, float* __restrict__ d_out) {
    int t = threadIdx.x;
    float s0 = 0, s1 = 0, s2 = 0, s3 = 0, s4 = 0;
    for (int bidx = t; bidx < NBLK; bidx += 256) {
        const float* P = part + (size_t)bidx * 8;
        s0 += P[0]; s1 += P[1]; s2 += P[2]; s3 += P[3]; s4 += P[4];
    }
    #pragma unroll
    for (int off = 32; off > 0; off >>= 1) {
        s0 += __shfl_down(s0, off); s1 += __shfl_down(s1, off);
        s2 += __shfl_down(s2, off); s3 += __shfl_down(s3, off);
        s4 += __shfl_down(s4, off);
    }
    __shared__ float red[4][5];
    if ((t & 63) == 0) {
        int w = t >> 6;
        red[w][0] = s0; red[w][1] = s1; red[w][2] = s2; red[w][3] = s3; red[w][4] = s4;
    }
    __syncthreads();
    if (t == 0) {
        float r0 = red[0][0] + red[1][0] + red[2][0] + red[3][0];
        float r1 = red[0][1] + red[1][1] + red[2][1] + red[3][1];
        float r2 = red[0][2] + red[1][2] + red[2][2] + red[3][2];
        float r3 = red[0][3] + red[1][3] + red[2][3] + red[3][3];
        float r4 = red[0][4] + red[1][4] + red[2][4] + red[3][4];
        d_out[0] = r0 + r1 + r2 + r3;
        d_out[1] = r0; d_out[2] = r1; d_out[3] = r2; d_out[4] = r3; d_out[5] = r4;
    }
}

extern "C" void kernel_launch(void* const* d_in, const int* in_sizes, int n_in,
                              void* d_out, int out_size, void* d_ws, size_t ws_size,
                              hipStream_t stream) {
    const float* xin    = (const float*)d_in[0];
    const float* labels = (const float*)d_in[1];
    const float* conv_w = (const float*)d_in[2];
    const float* conv_b = (const float*)d_in[3];
    float* out  = (float*)d_out;
    float* ws   = (float*)d_ws;
    float* part = ws + WS_PART_F;

    prep_kernel<<<259, 256, 0, stream>>>(conv_w, conv_b, labels, ws);
    conv5_kernel<<<5776 / 4, 256, 0, stream>>>(xin, ws, out);
    finalize_kernel<<<NBLK, 256, 0, stream>>>(xin, ws, out, part);
    finish_kernel<<<1, 256, 0, stream>>>(part, out);
}